// Round 5
// baseline (401.369 us; speedup 1.0000x reference)
//
#include <hip/hip_runtime.h>

// SplitLinear: out[b, o*C + c] = sum_s x[b, s*C + c] * w[o, s, c] + bias[o*C + c]
// x: [64, 1e6] fp32, w: [4, 400, 2500] fp32, bias: [10000], out: [64, 10000]
//
// R11: R4 post-mortem -- NSPLIT=4 doubled w L2-read volume and sized the
// per-XCD w slice at exactly L2 capacity (4 MB) -> thrash, +19.5 us. The
// invariant to preserve is R2's: 2 MB w-slice per XCD, L2-resident, x
// streamed past it with nontemporal loads.
// This round: split C (not S) across XCDs. Grid (8, 64); block (cb, b)
// computes FINAL out for one b-row x one 80-quad c-chunk, reducing all 400
// s in-register: no workspace, no reduce kernel, bias fused. Traffic =
// absolute floor (x 256 + w 16 + out 2.5 MB). Each XCD (wg%8=cb) keeps one
// 2 MB w c-slice hot; its 64 co-resident b-blocks re-read it from L2.
// Occupancy drops to 4 waves/CU, so prefetch depth carries Little's law:
// x depth 8 (~20.5 KB/CU in flight for the HBM stream), w depth 4 (L2
// latency). Modulo-8 unroll keeps all buffer indices compile-time.

constexpr int IN_F   = 1000000;
constexpr int S_DIM  = 400;
constexpr int C_DIM  = 2500;
constexpr int O_SETS = 4;
constexpr int B_SZ   = 64;
constexpr int OC     = O_SETS * C_DIM;    // 10000
constexpr int OUT_N  = B_SZ * OC;         // 640000

constexpr int NQ      = C_DIM / 4;        // 625 float4 quads per s-row
constexpr int NCHUNK  = 8;                // c-chunks == XCDs
constexpr int CHUNK   = 80;               // quads per chunk (last chunk: 65)
constexpr int THREADS = 128;              // 2 waves; lanes >= CHUNK return
constexpr int STEPQ   = NQ;               // float4 stride per s-step
constexpr int XD      = 8;                // x prefetch depth (HBM)
constexpr int WD      = 4;                // w prefetch depth (L2)

typedef float f4 __attribute__((ext_vector_type(4)));

__device__ __forceinline__ f4 ntload(const f4* p) {
    return __builtin_nontemporal_load(p);
}

__device__ __forceinline__ void fma4(f4& a, f4 p, f4 q) {
    a.x = fmaf(p.x, q.x, a.x);
    a.y = fmaf(p.y, q.y, a.y);
    a.z = fmaf(p.z, q.z, a.z);
    a.w = fmaf(p.w, q.w, a.w);
}

// grid (NCHUNK, B_SZ) = (8, 64), block = 128. One dispatch, no workspace.
__global__ __launch_bounds__(THREADS, 2) void sl_fused(const float* __restrict__ x,
                                                       const float* __restrict__ w,
                                                       const float* __restrict__ bias,
                                                       float* __restrict__ out) {
    const int tid = threadIdx.x;
    const int cb  = blockIdx.x;           // wg%8 -> one c-chunk per XCD
    const int b   = blockIdx.y;
    const int q   = cb * CHUNK + tid;     // global c-quad
    if (tid >= CHUNK || q >= NQ) return;  // no barriers/LDS: early exit safe

    const f4* xp = (const f4*)(x + (size_t)b * IN_F) + q;
    const f4* wp[O_SETS];
#pragma unroll
    for (int o = 0; o < O_SETS; ++o)
        wp[o] = (const f4*)(w + (size_t)o * (S_DIM * C_DIM)) + q;

    f4 acc[O_SETS];
#pragma unroll
    for (int o = 0; o < O_SETS; ++o) acc[o] = (f4)(0.f);

    // Software pipeline: x 8 steps ahead, w 4 steps ahead.
    f4 xb[XD];
    f4 wb[WD][O_SETS];
#pragma unroll
    for (int p = 0; p < XD; ++p) { xb[p] = ntload(xp); xp += STEPQ; }
#pragma unroll
    for (int p = 0; p < WD; ++p)
#pragma unroll
        for (int o = 0; o < O_SETS; ++o) { wb[p][o] = *wp[o]; wp[o] += STEPQ; }

    // Steady state: 49 iters x 8 steps. Step s: consume xb[s%8], wb[s%4];
    // then load x(s+8) and w(s+4) into the just-freed slots.
    for (int sb = 0; sb < S_DIM - 8; sb += 8) {
#pragma unroll
        for (int u = 0; u < 8; ++u) {
#pragma unroll
            for (int o = 0; o < O_SETS; ++o) fma4(acc[o], xb[u], wb[u % WD][o]);
            xb[u] = ntload(xp); xp += STEPQ;
#pragma unroll
            for (int o = 0; o < O_SETS; ++o) { wb[u % WD][o] = *wp[o]; wp[o] += STEPQ; }
        }
    }
    // Tail: steps 392..395 (still loading w 396..399), then 396..399.
#pragma unroll
    for (int u = 0; u < 4; ++u) {
#pragma unroll
        for (int o = 0; o < O_SETS; ++o) fma4(acc[o], xb[u], wb[u][o]);
#pragma unroll
        for (int o = 0; o < O_SETS; ++o) { wb[u][o] = *wp[o]; wp[o] += STEPQ; }
    }
#pragma unroll
    for (int u = 4; u < 8; ++u) {
#pragma unroll
        for (int o = 0; o < O_SETS; ++o) fma4(acc[o], xb[u], wb[u - 4][o]);
    }

    // Epilogue: fuse bias, write final out (no ws, no second kernel).
    float* orow = out + (size_t)b * OC;
#pragma unroll
    for (int o = 0; o < O_SETS; ++o) {
        f4 bv = *(const f4*)(bias + o * C_DIM + q * 4);
        f4 r;
        r.x = acc[o].x + bv.x;
        r.y = acc[o].y + bv.y;
        r.z = acc[o].z + bv.z;
        r.w = acc[o].w + bv.w;
        __builtin_nontemporal_store(r, (f4*)(orow + o * C_DIM + q * 4));
    }
}

extern "C" void kernel_launch(void* const* d_in, const int* in_sizes, int n_in,
                              void* d_out, int out_size, void* d_ws, size_t ws_size,
                              hipStream_t stream) {
    const float* x    = (const float*)d_in[0];
    const float* wgt  = (const float*)d_in[1];
    const float* bias = (const float*)d_in[2];
    float* out = (float*)d_out;

    dim3 g(NCHUNK, B_SZ);
    sl_fused<<<g, THREADS, 0, stream>>>(x, wgt, bias, out);
}

// Round 6
// 367.157 us; speedup vs baseline: 1.0932x; 1.0932x over previous
//
#include <hip/hip_runtime.h>

// SplitLinear: out[b, o*C + c] = sum_s x[b, s*C + c] * w[o, s, c] + bias[o*C + c]
// x: [64, 1e6] fp32, w: [4, 400, 2500] fp32, bias: [10000], out: [64, 10000]
//
// R12: RESTORE of the best verified kernel (R2 = 366.65 us). Session search
// summary: timed region = ~310 us unconditional harness fills + ~57 us of
// kernel time; this config runs ~88% of its structural roofline (315 MB @
// 6.3 TB/s). All three structural attempts to shave the remaining ~10 us
// regressed: atomic epilogue +52 us (fp32 atomicAdd serialization),
// NSPLIT=4 +19 us (4 MB w-slice = L2 capacity -> thrash), fused c-split
// +35 us (4 waves/CU latency-bound). Winning invariants, all A/B-verified:
//  - NSPLIT=8, z=wg%8: one 2 MB w-slice per XCD L2, comfortably resident
//  - nontemporal x loads / ws stores keep the use-once streams out of L2
//  - 640-thr blocks span a full 10 KB s-row (contiguous 6-stream advance)
//  - depth-3 register rotation (12 loads in flight/wave)
//  - ws round-trip at NSPLIT=8 (20.5 MB each way) + tiny reduce kernel

constexpr int IN_F   = 1000000;
constexpr int S_DIM  = 400;
constexpr int C_DIM  = 2500;
constexpr int O_SETS = 4;
constexpr int B_SZ   = 64;
constexpr int OC     = O_SETS * C_DIM;    // 10000
constexpr int OUT_N  = B_SZ * OC;         // 640000

constexpr int NQ      = C_DIM / 4;        // 625 float4 quads per s-row
constexpr int THREADS = 640;              // 10 waves, covers one full s-row
constexpr int NSPLIT  = 8;                // s segments, one per XCD
constexpr int SSEG    = S_DIM / NSPLIT;   // 50 s-steps per segment
constexpr int BT      = 2;                // b rows per thread
constexpr int BGRP    = B_SZ / BT;        // 32
constexpr int STEPQ   = NQ;               // float4 stride per s-step (contig)

constexpr size_t WS_NEED = (size_t)NSPLIT * OUT_N * sizeof(float);  // 20.5 MB

typedef float f4 __attribute__((ext_vector_type(4)));

__device__ __forceinline__ f4 ntload(const f4* p) {
    return __builtin_nontemporal_load(p);
}

__device__ __forceinline__ void fma4(f4& a, f4 p, f4 q) {
    a.x = fmaf(p.x, q.x, a.x);
    a.y = fmaf(p.y, q.y, a.y);
    a.z = fmaf(p.z, q.z, a.z);
    a.w = fmaf(p.w, q.w, a.w);
}

// ---------------- Main path ----------------

// grid (NSPLIT, BGRP), block = 640 thr. Thread tid -> c-quad tid (block spans
// one complete 10 KB s-row); BT=2 b-rows, 4 o-sets, acc over SSEG=50 s-steps.
// z = blockIdx.x -> wg%8 -> one 2 MB w-slice per XCD L2.
__global__ __launch_bounds__(THREADS, 3) void sl_part(const float* __restrict__ x,
                                                      const float* __restrict__ w,
                                                      float* __restrict__ ws) {
    const int tid = threadIdx.x;
    const bool act = (tid < NQ);
    const int q   = act ? tid : NQ - 1;   // clamp: junk loads stay in-bounds
    const int z   = blockIdx.x;
    const int b0  = blockIdx.y * BT;
    const int s0  = z * SSEG;

    const f4* xp[BT];
#pragma unroll
    for (int i = 0; i < BT; ++i)
        xp[i] = (const f4*)(x + (size_t)(b0 + i) * IN_F + (size_t)s0 * C_DIM) + q;

    const f4* wp[O_SETS];
#pragma unroll
    for (int o = 0; o < O_SETS; ++o)
        wp[o] = (const f4*)(w + (size_t)o * (S_DIM * C_DIM) + (size_t)s0 * C_DIM) + q;

    f4 acc[BT][O_SETS];
#pragma unroll
    for (int i = 0; i < BT; ++i)
#pragma unroll
        for (int o = 0; o < O_SETS; ++o)
            acc[i][o] = (f4)(0.f);

    // Depth-3 rotation: 12 loads (12 KB/wave) in flight while 32 fma run.
    // All indices compile-time after full unroll (rule: no runtime-indexed
    // register arrays).
    f4 xb[3][BT], wb[3][O_SETS];
#pragma unroll
    for (int p = 0; p < 2; ++p) {
#pragma unroll
        for (int i = 0; i < BT; ++i) { xb[p][i] = ntload(xp[i]); xp[i] += STEPQ; }
#pragma unroll
        for (int o = 0; o < O_SETS; ++o) { wb[p][o] = *wp[o]; wp[o] += STEPQ; }
    }

#pragma unroll
    for (int s = 0; s < SSEG; ++s) {
        const int cur = s % 3;
        const int nxt = (s + 2) % 3;
        if (s + 2 < SSEG) {   // compile-time after full unroll
#pragma unroll
            for (int i = 0; i < BT; ++i) { xb[nxt][i] = ntload(xp[i]); xp[i] += STEPQ; }
#pragma unroll
            for (int o = 0; o < O_SETS; ++o) { wb[nxt][o] = *wp[o]; wp[o] += STEPQ; }
        }
#pragma unroll
        for (int i = 0; i < BT; ++i)
#pragma unroll
            for (int o = 0; o < O_SETS; ++o)
                fma4(acc[i][o], xb[cur][i], wb[cur][o]);
    }

    if (act) {
        float* base = ws + (size_t)z * OUT_N;
#pragma unroll
        for (int i = 0; i < BT; ++i) {
            float* orow = base + (size_t)(b0 + i) * OC;
#pragma unroll
            for (int o = 0; o < O_SETS; ++o)
                __builtin_nontemporal_store(acc[i][o],
                                            (f4*)(orow + o * C_DIM + q * 4));
        }
    }
}

// out[idx] = bias[idx % OC] + sum_z ws[z][idx]
__global__ __launch_bounds__(256) void sl_reduce(const float* __restrict__ ws,
                                                 const float* __restrict__ bias,
                                                 float* __restrict__ out) {
    const int t = blockIdx.x * 256 + threadIdx.x;
    if (t >= OUT_N / 4) return;
    const int idx = t * 4;
    const int oc  = idx % OC;   // OC % 4 == 0 -> a float4 never crosses rows

    f4 s0 = *(const f4*)(bias + oc);
    f4 s1 = (f4)(0.f);
#pragma unroll
    for (int z = 0; z < NSPLIT; z += 2) {
        f4 v0 = ntload((const f4*)(ws + (size_t)z * OUT_N + idx));
        f4 v1 = ntload((const f4*)(ws + (size_t)(z + 1) * OUT_N + idx));
        s0.x += v0.x; s0.y += v0.y; s0.z += v0.z; s0.w += v0.w;
        s1.x += v1.x; s1.y += v1.y; s1.z += v1.z; s1.w += v1.w;
    }
    s0.x += s1.x; s0.y += s1.y; s0.z += s1.z; s0.w += s1.w;
    __builtin_nontemporal_store(s0, (f4*)(out + idx));
}

// ---------------- Fallback (ws too small): atomics ----------------

__global__ __launch_bounds__(256) void sl_init(const float* __restrict__ bias,
                                               float* __restrict__ out) {
    int j = blockIdx.x * 256 + threadIdx.x;
    if (j < OC) out[(size_t)blockIdx.y * OC + j] = bias[j];
}

__global__ __launch_bounds__(64) void sl_atomic(const float* __restrict__ x,
                                                const float* __restrict__ w,
                                                float* __restrict__ out) {
    const int lane = threadIdx.x;
    const int qq   = blockIdx.x * 64 + lane;
    if (qq >= NQ) return;
    const int b  = blockIdx.y;
    const int s0 = blockIdx.z * SSEG;

    const f4* xp = (const f4*)(x + (size_t)b * IN_F + (size_t)s0 * C_DIM) + qq;
    const f4* wp[O_SETS];
#pragma unroll
    for (int o = 0; o < O_SETS; ++o)
        wp[o] = (const f4*)(w + (size_t)o * (S_DIM * C_DIM) + (size_t)s0 * C_DIM) + qq;

    f4 acc[O_SETS];
#pragma unroll
    for (int o = 0; o < O_SETS; ++o) acc[o] = (f4)(0.f);

    for (int s = 0; s < SSEG; ++s) {
        f4 xv = *xp; xp += STEPQ;
        f4 wv4[O_SETS];
#pragma unroll
        for (int o = 0; o < O_SETS; ++o) { wv4[o] = *wp[o]; wp[o] += STEPQ; }
#pragma unroll
        for (int o = 0; o < O_SETS; ++o) fma4(acc[o], xv, wv4[o]);
    }

    float* orow = out + (size_t)b * OC;
#pragma unroll
    for (int o = 0; o < O_SETS; ++o) {
        float* dst = orow + o * C_DIM + qq * 4;
        atomicAdd(dst + 0, acc[o].x);
        atomicAdd(dst + 1, acc[o].y);
        atomicAdd(dst + 2, acc[o].z);
        atomicAdd(dst + 3, acc[o].w);
    }
}

extern "C" void kernel_launch(void* const* d_in, const int* in_sizes, int n_in,
                              void* d_out, int out_size, void* d_ws, size_t ws_size,
                              hipStream_t stream) {
    const float* x    = (const float*)d_in[0];
    const float* wgt  = (const float*)d_in[1];
    const float* bias = (const float*)d_in[2];
    float* out = (float*)d_out;

    if (ws_size >= WS_NEED) {
        float* ws = (float*)d_ws;
        dim3 g(NSPLIT, BGRP);
        sl_part<<<g, THREADS, 0, stream>>>(x, wgt, ws);
        sl_reduce<<<(OUT_N / 4 + 255) / 256, 256, 0, stream>>>(ws, bias, out);
    } else {
        dim3 gInit((OC + 255) / 256, B_SZ);
        sl_init<<<gInit, 256, 0, stream>>>(bias, out);
        dim3 g((NQ + 63) / 64, B_SZ, NSPLIT);
        sl_atomic<<<g, 64, 0, stream>>>(x, wgt, out);
    }
}